// Round 6
// baseline (364.785 us; speedup 1.0000x reference)
//
#include <hip/hip_runtime.h>

#define NN 4096
#define KS 32
#define KN 5

typedef float f32x4 __attribute__((ext_vector_type(4)));

// ---------------------------------------------------------------------------
// Block roles in k_all (1024 threads each):
//   [0, 256)        matvec:  s_new = sigmoid(W @ (0.95 s) + 0.05 noise), 16 rows/blk
//   [256, 288)      pre:     per-spark pristine-row draw + top-5 (u is an input)
//   288             scan:    sequential 32-spark scan (spins for matvec+pre)
//   [289, 289+512)  decay:   decay+clamp W -> out[NN..], 8 float4/thread
// ---------------------------------------------------------------------------
#define NB_MV    256
#define NB_PRE   32
#define BID_SCAN (NB_MV + NB_PRE)          // 288
#define NB_DEC   512
#define GRID_ALL (BID_SCAN + 1 + NB_DEC)   // 801

// ---------------------------------------------------------------------------
// Workspace layout (bytes):
//   [0,     16384)   s_new f32[4096]                 (matvec blocks)
//   [16384, 16512)   pristine nxt i32[KS]            (pre blocks)
//   [16512, 17152)   pristine top-5 idx i32[KS*KN]   (pre blocks)
//   [17152, 17160)   counters {matvec_done, pre_done} (memset to 0 per call)
//   [17408, 22016)   modlist dump u32[KS*36]          (scan -> k_fix)
// ---------------------------------------------------------------------------
#define WS_NXT   16384
#define WS_TOPI  16512
#define WS_CTR   17152
#define WS_MOD   17408
#define WS_NEED  (size_t)(WS_MOD + KS * 36 * 4)

// merge two sorted-desc 5-lists (tie -> lower index), result into (av,ai)
__device__ __forceinline__ void merge5(float* av, int* ai,
                                       const float* bv2, const int* bi2) {
    float nv[KN]; int ni[KN];
    int pA = 0, pB = 0;
    #pragma unroll
    for (int q = 0; q < KN; ++q) {
        float va = av[pA];  int ia = ai[pA];
        float vb = bv2[pB]; int ib = bi2[pB];
        bool pickA = (va > vb) || (va == vb && ia < ib);
        if (pickA) { nv[q] = va; ni[q] = ia; ++pA; }
        else       { nv[q] = vb; ni[q] = ib; ++pB; }
    }
    #pragma unroll
    for (int q = 0; q < KN; ++q) { av[q] = nv[q]; ai[q] = ni[q]; }
}

// ---------------------------------------------------------------------------
// Exact f64 hierarchical CDF scan over relu(r)+1e-6 (4 elems/thread, 1024 thr).
// SHARED between pre blocks and scan fallback: pure f64 adds in a fixed
// association order -> bit-identical sampled index on both paths.
// ---------------------------------------------------------------------------
__device__ __forceinline__ void cdf_scan(const float r[4], int tid, int lane, int wid,
                                         double* wave_incl, double incl[4],
                                         double& a_out, double& ascan_out) {
    double a = 0.0;
    #pragma unroll
    for (int m = 0; m < 4; ++m) {
        a += (double)(fmaxf(r[m], 0.f) + 1e-6f);
        incl[m] = a;
    }
    double ascan = a;
    #pragma unroll
    for (int off = 1; off < 64; off <<= 1) {
        double o = __shfl_up(ascan, (unsigned)off, 64);
        if (lane >= off) ascan += o;
    }
    if (lane == 63) wave_incl[wid] = ascan;
    __syncthreads();                        // B1
    if (tid < 16) {
        double v = wave_incl[tid];
        #pragma unroll
        for (int off = 1; off < 16; off <<= 1) {
            double o = __shfl_up(v, (unsigned)off, 64);
            if (tid >= off) v += o;
        }
        wave_incl[tid] = v;
    }
    __syncthreads();                        // B2
    a_out = a;
    ascan_out = ascan;
}

// ---------------------------------------------------------------------------
// Block-wide top-5 of relu(r), (value desc, index asc).  dest[0..4] = indices.
// ---------------------------------------------------------------------------
__device__ __forceinline__ void block_top5(const float r[4], int tid, int lane, int wid,
                                           float* topv, int* topi, int* dest) {
    float bv[KN]; int bi[KN];
    #pragma unroll
    for (int m = 0; m < 4; ++m) { bv[m] = fmaxf(r[m], 0.f); bi[m] = tid * 4 + m; }
    bv[4] = -1.f; bi[4] = 0x7fffffff;
    #define CE(i, j) { if (bv[i] < bv[j] || (bv[i] == bv[j] && bi[i] > bi[j])) { \
        float tv = bv[i]; bv[i] = bv[j]; bv[j] = tv; \
        int   ti = bi[i]; bi[i] = bi[j]; bi[j] = ti; } }
    CE(0, 1) CE(2, 3) CE(0, 2) CE(1, 3) CE(1, 2)
    #undef CE
    #pragma unroll
    for (int off = 1; off < 64; off <<= 1) {
        float ov[KN]; int oi[KN];
        #pragma unroll
        for (int q = 0; q < KN; ++q) {
            ov[q] = __shfl_xor(bv[q], off, 64);
            oi[q] = __shfl_xor(bi[q], off, 64);
        }
        merge5(bv, bi, ov, oi);
    }
    if (lane == 0) {
        #pragma unroll
        for (int q = 0; q < KN; ++q) { topv[wid * KN + q] = bv[q]; topi[wid * KN + q] = bi[q]; }
    }
    __syncthreads();                        // B4
    if (tid < 16) {
        #pragma unroll
        for (int q = 0; q < KN; ++q) { bv[q] = topv[tid * KN + q]; bi[q] = topi[tid * KN + q]; }
        #pragma unroll
        for (int off = 1; off < 16; off <<= 1) {
            float ov[KN]; int oi[KN];
            #pragma unroll
            for (int q = 0; q < KN; ++q) {
                ov[q] = __shfl_xor(bv[q], off, 64);
                oi[q] = __shfl_xor(bi[q], off, 64);
            }
            merge5(bv, bi, ov, oi);
        }
        if (tid == 0) {
            #pragma unroll
            for (int q = 0; q < KN; ++q) dest[q] = bi[q];
        }
    }
    __syncthreads();                        // B5
}

__device__ __forceinline__ void signal_done(unsigned* ctr) {
    __syncthreads();            // all block stores drained (vmcnt before barrier)
    if (threadIdx.x == 0) {
        __threadfence();        // device-scope visibility (L2 writeback on CDNA4)
        __hip_atomic_fetch_add(ctr, 1u, __ATOMIC_RELEASE, __HIP_MEMORY_SCOPE_AGENT);
    }
}

// ---------------------------------------------------------------------------
// k_all: fused matvec + precompute + scan + decay (roles by blockIdx).
// Decay blocks race scan's <=1152 W-cell writes when reading W — benign:
// k_fix re-derives outW for every scan-modified cell after the kernel.
// Matvec/pre read PRISTINE W: the scan block spin-waits on their counters
// before its first W store (device-scope acquire/release handshake;
// only the scan block spins -> no deadlock, dispatch-order independent).
// ---------------------------------------------------------------------------
__global__ __launch_bounds__(1024, 8) void k_all(float* W,
                                                 const float* __restrict__ s,
                                                 const float* __restrict__ noise,
                                                 const float* __restrict__ energy_in,
                                                 const float* __restrict__ u_in,
                                                 const int* __restrict__ pos_in,
                                                 const int* __restrict__ age_in,
                                                 float* out,
                                                 char* wsb,
                                                 int use_pre) {
    __shared__ float  s_lds[NN];          // matvec: sdec / scan: s state (16 KB)
    __shared__ double wave_incl[16];
    __shared__ float  topv[16 * KN];
    __shared__ int    topi[16 * KN];
    __shared__ int    sh_top[KN];
    __shared__ int    sh_nxt;
    __shared__ unsigned int modlist[KS * 36];   // 4.6 KB
    __shared__ float  preval[KS * 36];          // 4.6 KB
    __shared__ float  res_pos[KS], res_en[KS], res_age[KS];
    __shared__ int    sh_pos[KS], sh_age[KS];
    __shared__ float  sh_u[KS], sh_en[KS];
    __shared__ unsigned char dirty[NN];   // 4 KB
    __shared__ int    prenxt_lds[KS];
    __shared__ int    topi_lds[KS * KN];

    int tid = threadIdx.x, lane = tid & 63, wid = tid >> 6;
    int bid = blockIdx.x;
    unsigned* ctrA = (unsigned*)(wsb + WS_CTR);     // matvec done
    unsigned* ctrB = ctrA + 1;                      // pre done

    if (bid >= BID_SCAN + 1) {
        // ================= DECAY: 8 float4/thread, plain stores ===========
        float* outW = out + NN;
        size_t base = (size_t)(bid - (BID_SCAN + 1)) * 8192 + tid;
        const f32x4* Wv = (const f32x4*)W;
        f32x4* Ov = (f32x4*)outW;
        f32x4 v[8];
        #pragma unroll
        for (int r = 0; r < 8; ++r) v[r] = Wv[base + r * 1024];
        #pragma unroll
        for (int r = 0; r < 8; ++r) {
            v[r].x = fminf(fmaxf(v[r].x * 0.999f, -2.f), 2.f);
            v[r].y = fminf(fmaxf(v[r].y * 0.999f, -2.f), 2.f);
            v[r].z = fminf(fmaxf(v[r].z * 0.999f, -2.f), 2.f);
            v[r].w = fminf(fmaxf(v[r].w * 0.999f, -2.f), 2.f);
            Ov[base + r * 1024] = v[r];
        }
        return;
    }

    if (bid < NB_MV) {
        // ================= MATVEC: 16 rows/block, zero-s fast path ========
        float* s_out = (float*)wsb;
        float4 sv = ((const float4*)s)[tid];
        int nz = (sv.x != 0.f || sv.y != 0.f || sv.z != 0.f || sv.w != 0.f) ? 1 : 0;
        float4 d;
        d.x = sv.x * 0.95f; d.y = sv.y * 0.95f;
        d.z = sv.z * 0.95f; d.w = sv.w * 0.95f;
        ((float4*)s_lds)[tid] = d;
        int anynz = __syncthreads_or(nz);
        int row = bid * 16 + wid;
        float acc = 0.f;
        if (anynz) {
            const float4* Wr = (const float4*)(W + (size_t)row * NN);
            for (int it = 0; it < 16; ++it) {
                float4 w = Wr[it * 64 + lane];
                int j = (it * 64 + lane) * 4;
                acc += w.x * s_lds[j] + w.y * s_lds[j + 1] + w.z * s_lds[j + 2] + w.w * s_lds[j + 3];
            }
        }
        for (int off = 32; off > 0; off >>= 1) acc += __shfl_down(acc, off, 64);
        if (lane == 0) {
            float y = acc + 0.05f * noise[row];
            s_out[row] = 1.0f / (1.0f + expf(-y));
        }
        signal_done(ctrA);
        return;
    }

    if (bid < BID_SCAN) {
        // ================= PRE: pristine-row draw + top-5 =================
        if (!use_pre) return;
        int kk = bid - NB_MV;
        int prev = pos_in[kk];
        float4 rv = *((const float4*)(W + (size_t)prev * NN) + tid);
        float r[4] = {rv.x, rv.y, rv.z, rv.w};

        if (tid == 0) sh_nxt = NN - 1;          // default when t >= total
        double incl[4], a, ascan;
        cdf_scan(r, tid, lane, wid, wave_incl, incl, a, ascan);   // B1+B2
        double waveExcl = (wid == 0) ? 0.0 : wave_incl[wid - 1];
        double total    = wave_incl[15];
        double thrIncl  = waveExcl + ascan;
        double thrExcl  = thrIncl - a;
        double t = (double)u_in[kk] * total;
        if (thrIncl > t && thrExcl <= t) {      // exactly one thread fires
            int found = 3;
            #pragma unroll
            for (int m = 0; m < 4; ++m)
                if (thrExcl + incl[m] > t) { found = m; break; }
            sh_nxt = tid * 4 + found;
        }
        __syncthreads();                        // B3
        if (tid == 0) ((int*)(wsb + WS_NXT))[kk] = sh_nxt;
        block_top5(r, tid, lane, wid, topv, topi,
                   (int*)(wsb + WS_TOPI) + kk * KN);
        signal_done(ctrB);
        return;
    }

    // ===================== SCAN (bid == BID_SCAN) =========================
    // wait for matvec (s_new) and pre results; acquire makes them visible
    if (tid == 0) {
        while (__hip_atomic_load(ctrA, __ATOMIC_ACQUIRE, __HIP_MEMORY_SCOPE_AGENT) < NB_MV)
            __builtin_amdgcn_s_sleep(2);
        if (use_pre)
            while (__hip_atomic_load(ctrB, __ATOMIC_ACQUIRE, __HIP_MEMORY_SCOPE_AGENT) < NB_PRE)
                __builtin_amdgcn_s_sleep(2);
        __threadfence();
    }
    __syncthreads();

    const float* s_in = (const float*)wsb;
    ((float4*)s_lds)[tid] = ((const float4*)s_in)[tid];
    ((unsigned int*)dirty)[tid] = 0u;     // 1024 uints == 4096 bytes
    if (tid < KS) {
        sh_pos[tid] = pos_in[tid];
        sh_age[tid] = age_in[tid];
        sh_u[tid]   = u_in[tid];
        sh_en[tid]  = energy_in[tid];
    }
    if (use_pre) {
        if (tid < KS)      prenxt_lds[tid] = ((const int*)(wsb + WS_NXT))[tid];
        if (tid < KS * KN) topi_lds[tid]   = ((const int*)(wsb + WS_TOPI))[tid];
    }
    __syncthreads();                      // P1

    if (use_pre) {
        // prefill modlist with clean-assumption addresses; gather pristine
        // values.  Dirty/fullTop iterations overwrite their 36 entries later.
        for (int i = tid; i < KS * 36; i += 1024) {
            int k = i / 36, j = i - k * 36;
            int pv = sh_pos[k], nx = prenxt_lds[k];
            int row, col;
            if (j == 0)       { row = nx;                      col = pv; }
            else if (j < 6)   { row = pv;                      col = topi_lds[k * KN + j - 1]; }
            else if (j < 11)  { row = topi_lds[k * KN + j - 6]; col = pv; }
            else { int q = j - 11; row = topi_lds[k * KN + q / KN]; col = topi_lds[k * KN + q % KN]; }
            unsigned a = (unsigned)(row * NN + col);
            modlist[i] = a;
            preval[i]  = W[a];
        }
    }
    if (tid < KS && sh_age[tid] < 5) s_lds[sh_pos[tid]] = 1.0f;   // same-value races benign
    __syncthreads();                      // P2 (drains gather loads + LDS)

    for (int k = 0; k < KS; ++k) {
        int prev = sh_pos[k];
        bool rowClean = (use_pre != 0) && (dirty[prev] == 0);   // block-uniform
        float r[4] = {0.f, 0.f, 0.f, 0.f};
        bool haveRow = false;
        int nxt;

        if (!rowClean) {
            // ---- FALLBACK: full row load + exact CDF recompute
            float4 rv = *((const float4*)(W + (size_t)prev * NN) + tid);
            r[0] = rv.x; r[1] = rv.y; r[2] = rv.z; r[3] = rv.w;
            haveRow = true;
            if (tid == 0) sh_nxt = NN - 1;
            double incl[4], a, ascan;
            cdf_scan(r, tid, lane, wid, wave_incl, incl, a, ascan);
            double waveExcl = (wid == 0) ? 0.0 : wave_incl[wid - 1];
            double total    = wave_incl[15];
            double thrIncl  = waveExcl + ascan;
            double thrExcl  = thrIncl - a;
            double t = (double)sh_u[k] * total;
            if (thrIncl > t && thrExcl <= t) {
                int found = 3;
                #pragma unroll
                for (int m = 0; m < 4; ++m)
                    if (thrExcl + incl[m] > t) { found = m; break; }
                sh_nxt = tid * 4 + found;
            }
            __syncthreads();                        // B3
            nxt = sh_nxt;
        } else {
            nxt = prenxt_lds[k];
        }

        bool fullTop = !rowClean || (nxt == prev);   // block-uniform
        if (fullTop && !haveRow) {
            float4 rv = *((const float4*)(W + (size_t)prev * NN) + tid);
            r[0] = rv.x; r[1] = rv.y; r[2] = rv.z; r[3] = rv.w;
            haveRow = true;
            __syncthreads();   // loads complete before tid0's edge write below
        }

        int t0 = 0, t1 = 0, t2 = 0, t3 = 0, t4 = 0;
        bool usePreval = false, edgeAlias = false;
        if (!fullTop) {
            t0 = topi_lds[k * KN + 0]; t1 = topi_lds[k * KN + 1];
            t2 = topi_lds[k * KN + 2]; t3 = topi_lds[k * KN + 3];
            t4 = topi_lds[k * KN + 4];
            edgeAlias = (nxt == t0) || (nxt == t1) || (nxt == t2) ||
                        (nxt == t3) || (nxt == t4);
            bool aliasP = (prev == t0) || (prev == t1) || (prev == t2) ||
                          (prev == t3) || (prev == t4);
            bool dn = (dirty[nxt] | dirty[t0] | dirty[t1] |
                       dirty[t2]  | dirty[t3] | dirty[t4]) != 0;
            usePreval = !dn && !edgeAlias && !aliasP;
        }

        float sprev = s_lds[prev];
        if (usePreval) {
            // ---- zero-load path: 36 distinct cells, values from LDS
            if (tid < 36) {
                unsigned a = modlist[k * 36 + tid];
                float v = preval[k * 36 + tid];
                float nv = (tid == 0) ? (v * 0.95f + sprev * 0.05f)
                         : (tid < 6)  ? (v + 0.01f)
                         : (tid < 11) ? (v + 0.005f)
                                      : (v + 0.003f);
                W[a] = nv;
            }
        } else {
            // ---- live-RMW path (proven)
            if (tid == 0) {
                size_t o = (size_t)nxt * NN + prev;
                W[o] = W[o] * 0.95f + sprev * 0.05f;
            }
            if (fullTop) {
                if (nxt == prev && tid == (prev >> 2)) {   // register fix-up
                    int m = prev & 3;
                    r[m] = r[m] * 0.95f + sprev * 0.05f;
                }
                block_top5(r, tid, lane, wid, topv, topi, sh_top);  // B4+B5
                t0 = sh_top[0]; t1 = sh_top[1]; t2 = sh_top[2];
                t3 = sh_top[3]; t4 = sh_top[4];
            } else {
                if (edgeAlias) __syncthreads();     // uniform condition
            }
            #define TOPQ(q) (fullTop ? sh_top[q] : topi_lds[k * KN + (q)])
            bool alias = (prev == t0) || (prev == t1) || (prev == t2) ||
                         (prev == t3) || (prev == t4);

            if (alias) {
                if (tid < KN) W[(size_t)prev * NN + TOPQ(tid)] += 0.01f;
                __syncthreads();
                if (tid < KN) W[(size_t)TOPQ(tid) * NN + prev] += 0.005f;
                __syncthreads();
                if (tid < KN * KN) W[(size_t)TOPQ(tid / KN) * NN + TOPQ(tid % KN)] += 0.003f;
            } else {
                if (tid < KN) {
                    W[(size_t)prev * NN + TOPQ(tid)] += 0.01f;
                    W[(size_t)TOPQ(tid) * NN + prev] += 0.005f;
                }
                if (tid >= 64 && tid < 64 + KN * KN) {
                    int q = tid - 64;
                    W[(size_t)TOPQ(q / KN) * NN + TOPQ(q % KN)] += 0.003f;
                }
            }

            if (tid < 36) {
                int row, col;
                if (tid == 0)       { row = nxt;             col = prev; }
                else if (tid < 6)   { row = prev;            col = TOPQ(tid - 1); }
                else if (tid < 11)  { row = TOPQ(tid - 6);   col = prev; }
                else { int q = tid - 11; row = TOPQ(q / KN); col = TOPQ(q % KN); }
                modlist[k * 36 + tid] = (unsigned)(row * NN + col);
            }
            #undef TOPQ
        }

        // ---- mark rows written this iteration
        if (tid == 0) { dirty[nxt] = 1; dirty[prev] = 1; }
        if (tid >= 128 && tid < 128 + KN) {
            int q = tid - 128;
            int tr = fullTop ? sh_top[q] : topi_lds[k * KN + q];
            dirty[tr] = 1;
        }

        // ---- energy decay, s deposit (pre-respawn), respawn bookkeeping
        if (tid == 0) {
            float en = sh_en[k] * 0.98f;
            s_lds[nxt] = en;
            int age = sh_age[k] + 1;
            int posn = nxt;
            if (en < 0.05f) { posn = k % NN; en = 1.0f; age = 0; }
            res_pos[k] = (float)posn;
            res_en[k]  = en;
            res_age[k] = (float)age;
        }
        __syncthreads();                        // B6
    }

    // outputs: s, tail (pos/energy/age); dump modlist for k_fix
    ((float4*)out)[tid] = ((float4*)s_lds)[tid];
    if (tid < KS) {
        float* tail = out + NN + (size_t)NN * NN;
        tail[tid]          = res_pos[tid];
        tail[KS + tid]     = res_en[tid];
        tail[2 * KS + tid] = res_age[tid];
    }
    for (int i = tid; i < KS * 36; i += 1024)
        ((unsigned*)(wsb + WS_MOD))[i] = modlist[i];
}

// ---------------------------------------------------------------------------
// k_fix: after k_all (kernel boundary = full coherence), re-derive the
// decayed output for every scan-modified W cell.  Duplicate indices write
// identical values: benign.
// ---------------------------------------------------------------------------
__global__ __launch_bounds__(576) void k_fix(const float* __restrict__ W,
                                             const char* __restrict__ wsb,
                                             float* __restrict__ out) {
    int i = blockIdx.x * 576 + threadIdx.x;     // 2 blocks x 576 = 1152
    unsigned idx = ((const unsigned*)(wsb + WS_MOD))[i];
    float v = W[idx] * 0.999f;
    v = fminf(fmaxf(v, -2.f), 2.f);
    (out + NN)[idx] = v;
}

extern "C" void kernel_launch(void* const* d_in, const int* in_sizes, int n_in,
                              void* d_out, int out_size, void* d_ws, size_t ws_size,
                              hipStream_t stream) {
    float*       W      = (float*)d_in[0];        // modified in place; harness restores
    const float* s      = (const float*)d_in[1];
    const float* noise  = (const float*)d_in[2];
    const float* energy = (const float*)d_in[3];
    const float* u      = (const float*)d_in[4];
    const int*   pos    = (const int*)d_in[5];
    const int*   age    = (const int*)d_in[6];
    float*       out    = (float*)d_out;

    int use_pre = (ws_size >= WS_NEED) ? 1 : 0;   // guard: ws comfortably larger in practice

    hipMemsetAsync((char*)d_ws + WS_CTR, 0, 8, stream);   // reset handshake counters
    k_all<<<GRID_ALL, 1024, 0, stream>>>(W, s, noise, energy, u, pos, age,
                                         out, (char*)d_ws, use_pre);
    k_fix<<<2, 576, 0, stream>>>(W, (const char*)d_ws, out);
}

// Round 7
// 153.004 us; speedup vs baseline: 2.3842x; 2.3842x over previous
//
#include <hip/hip_runtime.h>

#define NN 4096
#define KS 32
#define KN 5

typedef float f32x4 __attribute__((ext_vector_type(4)));   // native vec4 for nontemporal builtins

#define NB_DEC 512        // fat decay blocks: 8 float4/thread, 128 KB each

// ---------------------------------------------------------------------------
// Workspace layout (bytes):
//   [0,     16384)   s_new f32[4096]                 (written by k_front)
//   [16384, 16512)   pristine nxt i32[KS]            (written by k_front pre-blocks)
//   [16512, 17152)   pristine top-5 idx i32[KS*KN]   (written by k_front pre-blocks)
// ---------------------------------------------------------------------------
#define WS_NXT   16384
#define WS_TOPI  16512
#define WS_NEED  (size_t)(WS_TOPI + KS * KN * 4)

// merge two sorted-desc 5-lists (tie -> lower index), result into (av,ai)
__device__ __forceinline__ void merge5(float* av, int* ai,
                                       const float* bv2, const int* bi2) {
    float nv[KN]; int ni[KN];
    int pA = 0, pB = 0;
    #pragma unroll
    for (int q = 0; q < KN; ++q) {
        float va = av[pA];  int ia = ai[pA];
        float vb = bv2[pB]; int ib = bi2[pB];
        bool pickA = (va > vb) || (va == vb && ia < ib);
        if (pickA) { nv[q] = va; ni[q] = ia; ++pA; }
        else       { nv[q] = vb; ni[q] = ib; ++pB; }
    }
    #pragma unroll
    for (int q = 0; q < KN; ++q) { av[q] = nv[q]; ai[q] = ni[q]; }
}

// ---------------------------------------------------------------------------
// Exact f64 hierarchical CDF scan over relu(r)+1e-6 (4 elems/thread, 1024 thr).
// SHARED between k_front's pre-blocks and k_scan's fallback: pure f64 adds in
// a fixed association order -> bit-identical sampled index on both paths.
// ---------------------------------------------------------------------------
__device__ __forceinline__ void cdf_scan(const float r[4], int tid, int lane, int wid,
                                         double* wave_incl, double incl[4],
                                         double& a_out, double& ascan_out) {
    double a = 0.0;
    #pragma unroll
    for (int m = 0; m < 4; ++m) {
        a += (double)(fmaxf(r[m], 0.f) + 1e-6f);
        incl[m] = a;
    }
    double ascan = a;
    #pragma unroll
    for (int off = 1; off < 64; off <<= 1) {
        double o = __shfl_up(ascan, (unsigned)off, 64);
        if (lane >= off) ascan += o;
    }
    if (lane == 63) wave_incl[wid] = ascan;
    __syncthreads();                        // B1
    if (tid < 16) {
        double v = wave_incl[tid];
        #pragma unroll
        for (int off = 1; off < 16; off <<= 1) {
            double o = __shfl_up(v, (unsigned)off, 64);
            if (tid >= off) v += o;
        }
        wave_incl[tid] = v;
    }
    __syncthreads();                        // B2
    a_out = a;
    ascan_out = ascan;
}

// ---------------------------------------------------------------------------
// Block-wide top-5 of relu(r), (value desc, index asc).  dest[0..4] = indices.
// ---------------------------------------------------------------------------
__device__ __forceinline__ void block_top5(const float r[4], int tid, int lane, int wid,
                                           float* topv, int* topi, int* dest) {
    float bv[KN]; int bi[KN];
    #pragma unroll
    for (int m = 0; m < 4; ++m) { bv[m] = fmaxf(r[m], 0.f); bi[m] = tid * 4 + m; }
    bv[4] = -1.f; bi[4] = 0x7fffffff;
    #define CE(i, j) { if (bv[i] < bv[j] || (bv[i] == bv[j] && bi[i] > bi[j])) { \
        float tv = bv[i]; bv[i] = bv[j]; bv[j] = tv; \
        int   ti = bi[i]; bi[i] = bi[j]; bi[j] = ti; } }
    CE(0, 1) CE(2, 3) CE(0, 2) CE(1, 3) CE(1, 2)
    #undef CE
    #pragma unroll
    for (int off = 1; off < 64; off <<= 1) {
        float ov[KN]; int oi[KN];
        #pragma unroll
        for (int q = 0; q < KN; ++q) {
            ov[q] = __shfl_xor(bv[q], off, 64);
            oi[q] = __shfl_xor(bi[q], off, 64);
        }
        merge5(bv, bi, ov, oi);
    }
    if (lane == 0) {
        #pragma unroll
        for (int q = 0; q < KN; ++q) { topv[wid * KN + q] = bv[q]; topi[wid * KN + q] = bi[q]; }
    }
    __syncthreads();                        // B4
    if (tid < 16) {
        #pragma unroll
        for (int q = 0; q < KN; ++q) { bv[q] = topv[tid * KN + q]; bi[q] = topi[tid * KN + q]; }
        #pragma unroll
        for (int off = 1; off < 16; off <<= 1) {
            float ov[KN]; int oi[KN];
            #pragma unroll
            for (int q = 0; q < KN; ++q) {
                ov[q] = __shfl_xor(bv[q], off, 64);
                oi[q] = __shfl_xor(bi[q], off, 64);
            }
            merge5(bv, bi, ov, oi);
        }
        if (tid == 0) {
            #pragma unroll
            for (int q = 0; q < KN; ++q) dest[q] = bi[q];
        }
    }
    __syncthreads();                        // B5
}

// ---------------------------------------------------------------------------
// k_front: one kernel, three roles by blockIdx (1024 threads each):
//   blocks [0, 512):   decay+clamp a 8192-float4 slice of W into out[NN..],
//                      8 float4/thread (8 loads in flight — latency hiding),
//                      non-temporal stores keep W resident in L2/L3
//   blocks [0, 256):   additionally s_new = sigmoid(W @ (0.95*s) + 0.05*noise),
//                      16 rows/block (one per wave), zero-s fast path
//   blocks [512, 544): per-spark precompute on the PRISTINE row pos[k]:
//                      resolve the multinomial draw (u is an input!) via the
//                      same cdf_scan as k_scan's fallback (bit-identical) +
//                      pristine top-5 indices.
// ---------------------------------------------------------------------------
__global__ __launch_bounds__(1024) void k_front(const float* __restrict__ W,
                                                const float* __restrict__ s,
                                                const float* __restrict__ noise,
                                                float* __restrict__ s_out,
                                                float* __restrict__ outW,
                                                const int* __restrict__ pos_in,
                                                const float* __restrict__ u_in,
                                                char* __restrict__ wsb) {
    __shared__ float  sdec[NN];
    __shared__ double wave_incl[16];
    __shared__ float  topv[16 * KN];
    __shared__ int    topi[16 * KN];
    __shared__ int    sh_nxt;
    int tid = threadIdx.x, lane = tid & 63, wid = tid >> 6;
    int bid = blockIdx.x;

    if (bid < NB_DEC) {
        // ---- decay slice: 8 float4/thread, independent loads for ILP
        size_t base = (size_t)bid * 8192 + tid;
        const f32x4* Wv = (const f32x4*)W;
        f32x4* Ov = (f32x4*)outW;
        f32x4 v[8];
        #pragma unroll
        for (int r = 0; r < 8; ++r) v[r] = Wv[base + r * 1024];
        #pragma unroll
        for (int r = 0; r < 8; ++r) {
            v[r].x = fminf(fmaxf(v[r].x * 0.999f, -2.f), 2.f);
            v[r].y = fminf(fmaxf(v[r].y * 0.999f, -2.f), 2.f);
            v[r].z = fminf(fmaxf(v[r].z * 0.999f, -2.f), 2.f);
            v[r].w = fminf(fmaxf(v[r].w * 0.999f, -2.f), 2.f);
            __builtin_nontemporal_store(v[r], &Ov[base + r * 1024]);
        }

        if (bid < 256) {
            // ---- matvec: 16 rows per block, one per wave
            float4 sv = ((const float4*)s)[tid];
            int nz = (sv.x != 0.f || sv.y != 0.f || sv.z != 0.f || sv.w != 0.f) ? 1 : 0;
            float4 d;
            d.x = sv.x * 0.95f; d.y = sv.y * 0.95f;
            d.z = sv.z * 0.95f; d.w = sv.w * 0.95f;
            ((float4*)sdec)[tid] = d;
            int anynz = __syncthreads_or(nz);
            int row = bid * 16 + wid;
            float acc = 0.f;
            if (anynz) {
                const float4* Wr = (const float4*)(W + (size_t)row * NN);
                for (int it = 0; it < 16; ++it) {
                    float4 w = Wr[it * 64 + lane];
                    int j = (it * 64 + lane) * 4;
                    acc += w.x * sdec[j] + w.y * sdec[j + 1] + w.z * sdec[j + 2] + w.w * sdec[j + 3];
                }
            }
            for (int off = 32; off > 0; off >>= 1) acc += __shfl_down(acc, off, 64);
            if (lane == 0) {
                float y = acc + 0.05f * noise[row];
                s_out[row] = 1.0f / (1.0f + expf(-y));
            }
        }
    } else {
        // ---- per-spark precompute, kk = spark index
        int kk = bid - NB_DEC;
        int prev = pos_in[kk];
        float4 rv = *((const float4*)(W + (size_t)prev * NN) + tid);
        float r[4] = {rv.x, rv.y, rv.z, rv.w};

        if (tid == 0) sh_nxt = NN - 1;          // default when t >= total
        double incl[4], a, ascan;
        cdf_scan(r, tid, lane, wid, wave_incl, incl, a, ascan);   // B1+B2 inside
        double waveExcl = (wid == 0) ? 0.0 : wave_incl[wid - 1];
        double total    = wave_incl[15];
        double thrIncl  = waveExcl + ascan;
        double thrExcl  = thrIncl - a;
        double t = (double)u_in[kk] * total;
        if (thrIncl > t && thrExcl <= t) {      // exactly one thread fires
            int found = 3;
            #pragma unroll
            for (int m = 0; m < 4; ++m)
                if (thrExcl + incl[m] > t) { found = m; break; }
            sh_nxt = tid * 4 + found;
        }
        __syncthreads();                        // B3
        if (tid == 0) ((int*)(wsb + WS_NXT))[kk] = sh_nxt;

        block_top5(r, tid, lane, wid, topv, topi,
                   (int*)(wsb + WS_TOPI) + kk * KN);
    }
}

// ---------------------------------------------------------------------------
// k_scan: sequential 32-spark scan (round-5 code, unchanged/proven).
// PREVAL fast path: all 36 RMW cell addresses of a clean iteration are known
// at prologue, so their pristine values are gathered ONCE in parallel into
// LDS.  An iteration whose 7 touched rows {prev,nxt,t0..4} are all clean and
// alias-free issues 36 stores computed purely from LDS — zero global loads.
// Any prior store marks its row dirty, so "rows clean" => cells pristine.
// ---------------------------------------------------------------------------
__global__ __launch_bounds__(1024) void k_scan(float* __restrict__ W,
                                               const float* __restrict__ s_in,
                                               const float* __restrict__ energy_in,
                                               const float* __restrict__ u_in,
                                               const int* __restrict__ pos_in,
                                               const int* __restrict__ age_in,
                                               float* __restrict__ out,
                                               const char* __restrict__ wsb,
                                               int use_pre) {
    __shared__ float  s_lds[NN];          // 16 KB
    __shared__ double wave_incl[16];
    __shared__ float  topv[16 * KN];
    __shared__ int    topi[16 * KN];
    __shared__ int    sh_top[KN];
    __shared__ int    sh_nxt;
    __shared__ unsigned int modlist[KS * 36];   // 4.6 KB: modified W indices
    __shared__ float  preval[KS * 36];          // 4.6 KB: pristine cell values
    __shared__ float  res_pos[KS], res_en[KS], res_age[KS];
    __shared__ int    sh_pos[KS], sh_age[KS];
    __shared__ float  sh_u[KS], sh_en[KS];
    __shared__ unsigned char dirty[NN];   // 4 KB: rows written by the scan
    __shared__ int    prenxt_lds[KS];
    __shared__ int    topi_lds[KS * KN];

    int tid = threadIdx.x;
    int lane = tid & 63, wid = tid >> 6;

    ((float4*)s_lds)[tid] = ((const float4*)s_in)[tid];
    ((unsigned int*)dirty)[tid] = 0u;     // 1024 uints == 4096 bytes
    if (tid < KS) {
        sh_pos[tid] = pos_in[tid];
        sh_age[tid] = age_in[tid];
        sh_u[tid]   = u_in[tid];
        sh_en[tid]  = energy_in[tid];
    }
    if (use_pre) {
        if (tid < KS)      prenxt_lds[tid] = ((const int*)(wsb + WS_NXT))[tid];
        if (tid < KS * KN) topi_lds[tid]   = ((const int*)(wsb + WS_TOPI))[tid];
    }
    __syncthreads();                      // P1: sh_pos/prenxt/topi visible

    if (use_pre) {
        // prefill modlist with clean-assumption addresses; gather pristine
        // values.  Dirty/fullTop iterations overwrite their 36 entries later.
        for (int i = tid; i < KS * 36; i += 1024) {
            int k = i / 36, j = i - k * 36;
            int pv = sh_pos[k], nx = prenxt_lds[k];
            int row, col;
            if (j == 0)       { row = nx;                      col = pv; }
            else if (j < 6)   { row = pv;                      col = topi_lds[k * KN + j - 1]; }
            else if (j < 11)  { row = topi_lds[k * KN + j - 6]; col = pv; }
            else { int q = j - 11; row = topi_lds[k * KN + q / KN]; col = topi_lds[k * KN + q % KN]; }
            unsigned a = (unsigned)(row * NN + col);
            modlist[i] = a;
            preval[i]  = W[a];
        }
    }
    if (tid < KS && sh_age[tid] < 5) s_lds[sh_pos[tid]] = 1.0f;   // same-value races benign
    __syncthreads();                      // P2 (drains gather loads + LDS)

    for (int k = 0; k < KS; ++k) {
        int prev = sh_pos[k];
        bool rowClean = (use_pre != 0) && (dirty[prev] == 0);   // block-uniform
        float r[4] = {0.f, 0.f, 0.f, 0.f};
        bool haveRow = false;
        int nxt;

        if (!rowClean) {
            // ---- FALLBACK: full row load + exact CDF recompute (original path)
            float4 rv = *((const float4*)(W + (size_t)prev * NN) + tid);
            r[0] = rv.x; r[1] = rv.y; r[2] = rv.z; r[3] = rv.w;
            haveRow = true;
            if (tid == 0) sh_nxt = NN - 1;  // default when t >= total
            double incl[4], a, ascan;
            cdf_scan(r, tid, lane, wid, wave_incl, incl, a, ascan);
            double waveExcl = (wid == 0) ? 0.0 : wave_incl[wid - 1];
            double total    = wave_incl[15];
            double thrIncl  = waveExcl + ascan;
            double thrExcl  = thrIncl - a;
            double t = (double)sh_u[k] * total;
            if (thrIncl > t && thrExcl <= t) {      // exactly one thread fires
                int found = 3;
                #pragma unroll
                for (int m = 0; m < 4; ++m)
                    if (thrExcl + incl[m] > t) { found = m; break; }
                sh_nxt = tid * 4 + found;
            }
            __syncthreads();                        // B3
            nxt = sh_nxt;
        } else {
            // ---- FAST PATH: draw fully precomputed on the pristine row
            nxt = prenxt_lds[k];
        }

        // need the full row for top-5 when dirty OR when the edge update hits
        // this very row (nxt == prev); load it BEFORE the edge write
        bool fullTop = !rowClean || (nxt == prev);   // block-uniform
        if (fullTop && !haveRow) {
            float4 rv = *((const float4*)(W + (size_t)prev * NN) + tid);
            r[0] = rv.x; r[1] = rv.y; r[2] = rv.z; r[3] = rv.w;
            haveRow = true;
            __syncthreads();   // loads complete before tid0's edge write below
        }

        // PREVAL eligibility: all 7 touched rows clean (no prior store can
        // have hit any of the 36 cells) and no intra-iteration cell overlap
        // (alias/edgeAlias), so each cell's new value = f(pristine value).
        int t0 = 0, t1 = 0, t2 = 0, t3 = 0, t4 = 0;
        bool usePreval = false, edgeAlias = false;
        if (!fullTop) {
            t0 = topi_lds[k * KN + 0]; t1 = topi_lds[k * KN + 1];
            t2 = topi_lds[k * KN + 2]; t3 = topi_lds[k * KN + 3];
            t4 = topi_lds[k * KN + 4];
            edgeAlias = (nxt == t0) || (nxt == t1) || (nxt == t2) ||
                        (nxt == t3) || (nxt == t4);
            bool aliasP = (prev == t0) || (prev == t1) || (prev == t2) ||
                          (prev == t3) || (prev == t4);
            bool dn = (dirty[nxt] | dirty[t0] | dirty[t1] |
                       dirty[t2]  | dirty[t3] | dirty[t4]) != 0;
            usePreval = !dn && !edgeAlias && !aliasP;
        }

        float sprev = s_lds[prev];
        if (usePreval) {
            // ---- zero-load path: 36 distinct cells, values from LDS
            if (tid < 36) {
                unsigned a = modlist[k * 36 + tid];
                float v = preval[k * 36 + tid];
                float nv = (tid == 0) ? (v * 0.95f + sprev * 0.05f)
                         : (tid < 6)  ? (v + 0.01f)
                         : (tid < 11) ? (v + 0.005f)
                                      : (v + 0.003f);
                W[a] = nv;
            }
            // modlist already correct from prologue prefill
        } else {
            // ---- live-RMW path (round-3 code, proven)
            if (tid == 0) {
                size_t o = (size_t)nxt * NN + prev;
                W[o] = W[o] * 0.95f + sprev * 0.05f;
            }
            if (fullTop) {
                if (nxt == prev && tid == (prev >> 2)) {   // register fix-up
                    int m = prev & 3;
                    r[m] = r[m] * 0.95f + sprev * 0.05f;
                }
                block_top5(r, tid, lane, wid, topv, topi, sh_top);  // B4+B5 inside
                t0 = sh_top[0]; t1 = sh_top[1]; t2 = sh_top[2];
                t3 = sh_top[3]; t4 = sh_top[4];
            } else {
                // edge write ordered before ripple RMWs iff they can alias
                if (edgeAlias) __syncthreads();     // uniform condition
            }
            #define TOPQ(q) (fullTop ? sh_top[q] : topi_lds[k * KN + (q)])
            bool alias = (prev == t0) || (prev == t1) || (prev == t2) ||
                         (prev == t3) || (prev == t4);

            // ripples (plain stores; write-through L1 keeps them block-coherent)
            if (alias) {
                if (tid < KN) W[(size_t)prev * NN + TOPQ(tid)] += 0.01f;
                __syncthreads();
                if (tid < KN) W[(size_t)TOPQ(tid) * NN + prev] += 0.005f;
                __syncthreads();
                if (tid < KN * KN) W[(size_t)TOPQ(tid / KN) * NN + TOPQ(tid % KN)] += 0.003f;
            } else {
                if (tid < KN) {
                    W[(size_t)prev * NN + TOPQ(tid)] += 0.01f;
                    W[(size_t)TOPQ(tid) * NN + prev] += 0.005f;
                }
                if (tid >= 64 && tid < 64 + KN * KN) {
                    int q = tid - 64;
                    W[(size_t)TOPQ(q / KN) * NN + TOPQ(q % KN)] += 0.003f;
                }
            }

            // record modified W indices (overwrites clean-assumption prefill)
            if (tid < 36) {
                int row, col;
                if (tid == 0)       { row = nxt;             col = prev; }
                else if (tid < 6)   { row = prev;            col = TOPQ(tid - 1); }
                else if (tid < 11)  { row = TOPQ(tid - 6);   col = prev; }
                else { int q = tid - 11; row = TOPQ(q / KN); col = TOPQ(q % KN); }
                modlist[k * 36 + tid] = (unsigned)(row * NN + col);
            }
            #undef TOPQ
        }

        // ---- mark rows written this iteration (invalidates preval for them)
        if (tid == 0) { dirty[nxt] = 1; dirty[prev] = 1; }
        if (tid >= 128 && tid < 128 + KN) {
            int q = tid - 128;
            int tr = fullTop ? sh_top[q] : topi_lds[k * KN + q];
            dirty[tr] = 1;
        }

        // ---- energy decay, s deposit (pre-respawn), respawn bookkeeping
        if (tid == 0) {
            float en = sh_en[k] * 0.98f;
            s_lds[nxt] = en;
            int age = sh_age[k] + 1;
            int posn = nxt;
            if (en < 0.05f) { posn = k % NN; en = 1.0f; age = 0; }
            res_pos[k] = (float)posn;
            res_en[k]  = en;
            res_age[k] = (float)age;
        }
        __syncthreads();                        // B6: full drain (proven ordering)
    }

    // outputs: s, tail (pos/energy/age), then fix up scan-touched W entries
    ((float4*)out)[tid] = ((float4*)s_lds)[tid];
    if (tid < KS) {
        float* tail = out + NN + (size_t)NN * NN;
        tail[tid]          = res_pos[tid];
        tail[KS + tid]     = res_en[tid];
        tail[2 * KS + tid] = res_age[tid];
    }
    float* outW = out + NN;
    for (int i = tid; i < KS * 36; i += 1024) {
        unsigned idx = modlist[i];
        float v = W[idx] * 0.999f;
        v = fminf(fmaxf(v, -2.f), 2.f);
        outW[idx] = v;   // duplicate indices write identical values: benign
    }
}

extern "C" void kernel_launch(void* const* d_in, const int* in_sizes, int n_in,
                              void* d_out, int out_size, void* d_ws, size_t ws_size,
                              hipStream_t stream) {
    float*       W      = (float*)d_in[0];        // modified in place; harness restores
    const float* s      = (const float*)d_in[1];
    const float* noise  = (const float*)d_in[2];
    const float* energy = (const float*)d_in[3];
    const float* u      = (const float*)d_in[4];
    const int*   pos    = (const int*)d_in[5];
    const int*   age    = (const int*)d_in[6];
    float*       out    = (float*)d_out;
    float*       s_ws   = (float*)d_ws;           // s_new lives at ws offset 0

    int use_pre = (ws_size >= WS_NEED) ? 1 : 0;   // guard: fall back if ws too small

    k_front<<<NB_DEC + (use_pre ? KS : 0), 1024, 0, stream>>>(
        W, s, noise, s_ws, out + NN, pos, u, (char*)d_ws);
    k_scan<<<1, 1024, 0, stream>>>(W, s_ws, energy, u, pos, age, out,
                                   (const char*)d_ws, use_pre);
}

// Round 8
// 148.423 us; speedup vs baseline: 2.4577x; 1.0309x over previous
//
#include <hip/hip_runtime.h>

#define NN 4096
#define KS 32
#define KN 5

typedef float f32x4 __attribute__((ext_vector_type(4)));   // native vec4 for nontemporal builtins

#define NB_DEC   512      // serial-fallback k_front decay blocks
#define NB_COMBO 512      // combo grid: bid0 = scan, bid1..511 = decay (bid511 does 2 slices)

// ---------------------------------------------------------------------------
// Workspace layout (bytes):
//   [0,     16384)   s_new f32[4096]                 (k_mvpre matvec blocks)
//   [16384, 16512)   pristine nxt i32[KS]            (k_mvpre pre blocks)
//   [16512, 17152)   pristine top-5 idx i32[KS*KN]   (k_mvpre pre blocks)
//   [17408, 22016)   modlist dump u32[KS*36]         (k_combo scan -> k_fix)
// ---------------------------------------------------------------------------
#define WS_NXT   16384
#define WS_TOPI  16512
#define WS_MOD   17408
#define WS_NEED  (size_t)(WS_MOD + KS * 36 * 4)

// merge two sorted-desc 5-lists (tie -> lower index), result into (av,ai)
__device__ __forceinline__ void merge5(float* av, int* ai,
                                       const float* bv2, const int* bi2) {
    float nv[KN]; int ni[KN];
    int pA = 0, pB = 0;
    #pragma unroll
    for (int q = 0; q < KN; ++q) {
        float va = av[pA];  int ia = ai[pA];
        float vb = bv2[pB]; int ib = bi2[pB];
        bool pickA = (va > vb) || (va == vb && ia < ib);
        if (pickA) { nv[q] = va; ni[q] = ia; ++pA; }
        else       { nv[q] = vb; ni[q] = ib; ++pB; }
    }
    #pragma unroll
    for (int q = 0; q < KN; ++q) { av[q] = nv[q]; ai[q] = ni[q]; }
}

// ---------------------------------------------------------------------------
// Exact f64 hierarchical CDF scan over relu(r)+1e-6 (4 elems/thread, 1024 thr).
// SHARED between pre blocks and scan fallback: pure f64 adds in a fixed
// association order -> bit-identical sampled index on both paths.
// ---------------------------------------------------------------------------
__device__ __forceinline__ void cdf_scan(const float r[4], int tid, int lane, int wid,
                                         double* wave_incl, double incl[4],
                                         double& a_out, double& ascan_out) {
    double a = 0.0;
    #pragma unroll
    for (int m = 0; m < 4; ++m) {
        a += (double)(fmaxf(r[m], 0.f) + 1e-6f);
        incl[m] = a;
    }
    double ascan = a;
    #pragma unroll
    for (int off = 1; off < 64; off <<= 1) {
        double o = __shfl_up(ascan, (unsigned)off, 64);
        if (lane >= off) ascan += o;
    }
    if (lane == 63) wave_incl[wid] = ascan;
    __syncthreads();                        // B1
    if (tid < 16) {
        double v = wave_incl[tid];
        #pragma unroll
        for (int off = 1; off < 16; off <<= 1) {
            double o = __shfl_up(v, (unsigned)off, 64);
            if (tid >= off) v += o;
        }
        wave_incl[tid] = v;
    }
    __syncthreads();                        // B2
    a_out = a;
    ascan_out = ascan;
}

// ---------------------------------------------------------------------------
// Block-wide top-5 of relu(r), (value desc, index asc).  dest[0..4] = indices.
// ---------------------------------------------------------------------------
__device__ __forceinline__ void block_top5(const float r[4], int tid, int lane, int wid,
                                           float* topv, int* topi, int* dest) {
    float bv[KN]; int bi[KN];
    #pragma unroll
    for (int m = 0; m < 4; ++m) { bv[m] = fmaxf(r[m], 0.f); bi[m] = tid * 4 + m; }
    bv[4] = -1.f; bi[4] = 0x7fffffff;
    #define CE(i, j) { if (bv[i] < bv[j] || (bv[i] == bv[j] && bi[i] > bi[j])) { \
        float tv = bv[i]; bv[i] = bv[j]; bv[j] = tv; \
        int   ti = bi[i]; bi[i] = bi[j]; bi[j] = ti; } }
    CE(0, 1) CE(2, 3) CE(0, 2) CE(1, 3) CE(1, 2)
    #undef CE
    #pragma unroll
    for (int off = 1; off < 64; off <<= 1) {
        float ov[KN]; int oi[KN];
        #pragma unroll
        for (int q = 0; q < KN; ++q) {
            ov[q] = __shfl_xor(bv[q], off, 64);
            oi[q] = __shfl_xor(bi[q], off, 64);
        }
        merge5(bv, bi, ov, oi);
    }
    if (lane == 0) {
        #pragma unroll
        for (int q = 0; q < KN; ++q) { topv[wid * KN + q] = bv[q]; topi[wid * KN + q] = bi[q]; }
    }
    __syncthreads();                        // B4
    if (tid < 16) {
        #pragma unroll
        for (int q = 0; q < KN; ++q) { bv[q] = topv[tid * KN + q]; bi[q] = topi[tid * KN + q]; }
        #pragma unroll
        for (int off = 1; off < 16; off <<= 1) {
            float ov[KN]; int oi[KN];
            #pragma unroll
            for (int q = 0; q < KN; ++q) {
                ov[q] = __shfl_xor(bv[q], off, 64);
                oi[q] = __shfl_xor(bi[q], off, 64);
            }
            merge5(bv, bi, ov, oi);
        }
        if (tid == 0) {
            #pragma unroll
            for (int q = 0; q < KN; ++q) dest[q] = bi[q];
        }
    }
    __syncthreads();                        // B5
}

// decay+clamp one 8192-float4 slice of W into outW (8 loads in flight, NT store)
__device__ __forceinline__ void decay_slice(const float* W, float* outW, int d, int tid) {
    size_t base = (size_t)d * 8192 + tid;
    const f32x4* Wv = (const f32x4*)W;
    f32x4* Ov = (f32x4*)outW;
    f32x4 v[8];
    #pragma unroll
    for (int r = 0; r < 8; ++r) v[r] = Wv[base + r * 1024];
    #pragma unroll
    for (int r = 0; r < 8; ++r) {
        v[r].x = fminf(fmaxf(v[r].x * 0.999f, -2.f), 2.f);
        v[r].y = fminf(fmaxf(v[r].y * 0.999f, -2.f), 2.f);
        v[r].z = fminf(fmaxf(v[r].z * 0.999f, -2.f), 2.f);
        v[r].w = fminf(fmaxf(v[r].w * 0.999f, -2.f), 2.f);
        __builtin_nontemporal_store(v[r], &Ov[base + r * 1024]);
    }
}

// ---------------------------------------------------------------------------
// k_mvpre: matvec (blocks [0,256), 16 rows each, zero-s fast path) +
// per-spark precompute (blocks [256,288)) on PRISTINE W.  Runs before
// k_combo; the kernel boundary makes its outputs coherent for the scan.
// ---------------------------------------------------------------------------
__global__ __launch_bounds__(1024) void k_mvpre(const float* __restrict__ W,
                                                const float* __restrict__ s,
                                                const float* __restrict__ noise,
                                                float* __restrict__ s_out,
                                                const int* __restrict__ pos_in,
                                                const float* __restrict__ u_in,
                                                char* __restrict__ wsb) {
    __shared__ float  sdec[NN];
    __shared__ double wave_incl[16];
    __shared__ float  topv[16 * KN];
    __shared__ int    topi[16 * KN];
    __shared__ int    sh_nxt;
    int tid = threadIdx.x, lane = tid & 63, wid = tid >> 6;
    int bid = blockIdx.x;

    if (bid < 256) {
        // ---- matvec: 16 rows per block, one per wave
        float4 sv = ((const float4*)s)[tid];
        int nz = (sv.x != 0.f || sv.y != 0.f || sv.z != 0.f || sv.w != 0.f) ? 1 : 0;
        float4 d;
        d.x = sv.x * 0.95f; d.y = sv.y * 0.95f;
        d.z = sv.z * 0.95f; d.w = sv.w * 0.95f;
        ((float4*)sdec)[tid] = d;
        int anynz = __syncthreads_or(nz);
        int row = bid * 16 + wid;
        float acc = 0.f;
        if (anynz) {
            const float4* Wr = (const float4*)(W + (size_t)row * NN);
            for (int it = 0; it < 16; ++it) {
                float4 w = Wr[it * 64 + lane];
                int j = (it * 64 + lane) * 4;
                acc += w.x * sdec[j] + w.y * sdec[j + 1] + w.z * sdec[j + 2] + w.w * sdec[j + 3];
            }
        }
        for (int off = 32; off > 0; off >>= 1) acc += __shfl_down(acc, off, 64);
        if (lane == 0) {
            float y = acc + 0.05f * noise[row];
            s_out[row] = 1.0f / (1.0f + expf(-y));
        }
    } else {
        // ---- per-spark precompute on pristine row pos[kk]
        int kk = bid - 256;
        int prev = pos_in[kk];
        float4 rv = *((const float4*)(W + (size_t)prev * NN) + tid);
        float r[4] = {rv.x, rv.y, rv.z, rv.w};

        if (tid == 0) sh_nxt = NN - 1;          // default when t >= total
        double incl[4], a, ascan;
        cdf_scan(r, tid, lane, wid, wave_incl, incl, a, ascan);   // B1+B2
        double waveExcl = (wid == 0) ? 0.0 : wave_incl[wid - 1];
        double total    = wave_incl[15];
        double thrIncl  = waveExcl + ascan;
        double thrExcl  = thrIncl - a;
        double t = (double)u_in[kk] * total;
        if (thrIncl > t && thrExcl <= t) {      // exactly one thread fires
            int found = 3;
            #pragma unroll
            for (int m = 0; m < 4; ++m)
                if (thrExcl + incl[m] > t) { found = m; break; }
            sh_nxt = tid * 4 + found;
        }
        __syncthreads();                        // B3
        if (tid == 0) ((int*)(wsb + WS_NXT))[kk] = sh_nxt;

        block_top5(r, tid, lane, wid, topv, topi,
                   (int*)(wsb + WS_TOPI) + kk * KN);
    }
}

// ---------------------------------------------------------------------------
// k_front (serial-fallback only): round-7 fat decay + matvec riding on the
// first 256 blocks.  s_out may be out[0..NN) when ws is too small.
// ---------------------------------------------------------------------------
__global__ __launch_bounds__(1024) void k_front(const float* __restrict__ W,
                                                const float* __restrict__ s,
                                                const float* __restrict__ noise,
                                                float* __restrict__ s_out,
                                                float* __restrict__ outW) {
    __shared__ float sdec[NN];
    int tid = threadIdx.x, lane = tid & 63, wid = tid >> 6;
    int bid = blockIdx.x;

    decay_slice(W, outW, bid, tid);

    if (bid < 256) {
        float4 sv = ((const float4*)s)[tid];
        int nz = (sv.x != 0.f || sv.y != 0.f || sv.z != 0.f || sv.w != 0.f) ? 1 : 0;
        float4 d;
        d.x = sv.x * 0.95f; d.y = sv.y * 0.95f;
        d.z = sv.z * 0.95f; d.w = sv.w * 0.95f;
        ((float4*)sdec)[tid] = d;
        int anynz = __syncthreads_or(nz);
        int row = bid * 16 + wid;
        float acc = 0.f;
        if (anynz) {
            const float4* Wr = (const float4*)(W + (size_t)row * NN);
            for (int it = 0; it < 16; ++it) {
                float4 w = Wr[it * 64 + lane];
                int j = (it * 64 + lane) * 4;
                acc += w.x * sdec[j] + w.y * sdec[j + 1] + w.z * sdec[j + 2] + w.w * sdec[j + 3];
            }
        }
        for (int off = 32; off > 0; off >>= 1) acc += __shfl_down(acc, off, 64);
        if (lane == 0) {
            float y = acc + 0.05f * noise[row];
            s_out[row] = 1.0f / (1.0f + expf(-y));
        }
    }
}

// ---------------------------------------------------------------------------
// k_combo: bid 0 = sequential 32-spark scan (round-5/7 proven body);
// bids 1..511 = decay slices (bid 511 does two).  NO inter-block waits:
// the scan's inputs (s_new, pre results) are coherent via the preceding
// kernel boundary.  Decay reads of W racing scan's <=1152 cell writes give
// possibly-stale outW values for exactly those cells — k_fix re-derives
// them after the kernel.  In serial-fallback mode (gridDim.x == 1) the scan
// does the outW fixup internally (decay already ran in k_front).
// ---------------------------------------------------------------------------
__global__ __launch_bounds__(1024) void k_combo(float* W,
                                                const float* s_in,
                                                const float* __restrict__ energy_in,
                                                const float* __restrict__ u_in,
                                                const int* __restrict__ pos_in,
                                                const int* __restrict__ age_in,
                                                float* out,
                                                char* wsb,
                                                int use_pre) {
    __shared__ float  s_lds[NN];          // 16 KB
    __shared__ double wave_incl[16];
    __shared__ float  topv[16 * KN];
    __shared__ int    topi[16 * KN];
    __shared__ int    sh_top[KN];
    __shared__ int    sh_nxt;
    __shared__ unsigned int modlist[KS * 36];   // 4.6 KB: modified W indices
    __shared__ float  preval[KS * 36];          // 4.6 KB: pristine cell values
    __shared__ float  res_pos[KS], res_en[KS], res_age[KS];
    __shared__ int    sh_pos[KS], sh_age[KS];
    __shared__ float  sh_u[KS], sh_en[KS];
    __shared__ unsigned char dirty[NN];   // 4 KB: rows written by the scan
    __shared__ int    prenxt_lds[KS];
    __shared__ int    topi_lds[KS * KN];

    int tid = threadIdx.x;
    int lane = tid & 63, wid = tid >> 6;
    int bid = blockIdx.x;

    if (bid > 0) {
        // ================== DECAY (no dependency on the scan) =============
        decay_slice(W, out + NN, bid - 1, tid);
        if (bid == NB_COMBO - 1) decay_slice(W, out + NN, NB_COMBO - 1, tid);
        return;
    }

    // ===================== SCAN (bid == 0, proven body) ===================
    ((float4*)s_lds)[tid] = ((const float4*)s_in)[tid];
    ((unsigned int*)dirty)[tid] = 0u;     // 1024 uints == 4096 bytes
    if (tid < KS) {
        sh_pos[tid] = pos_in[tid];
        sh_age[tid] = age_in[tid];
        sh_u[tid]   = u_in[tid];
        sh_en[tid]  = energy_in[tid];
    }
    if (use_pre) {
        if (tid < KS)      prenxt_lds[tid] = ((const int*)(wsb + WS_NXT))[tid];
        if (tid < KS * KN) topi_lds[tid]   = ((const int*)(wsb + WS_TOPI))[tid];
    }
    __syncthreads();                      // P1: sh_pos/prenxt/topi visible

    if (use_pre) {
        // prefill modlist with clean-assumption addresses; gather pristine
        // values.  Dirty/fullTop iterations overwrite their 36 entries later.
        for (int i = tid; i < KS * 36; i += 1024) {
            int k = i / 36, j = i - k * 36;
            int pv = sh_pos[k], nx = prenxt_lds[k];
            int row, col;
            if (j == 0)       { row = nx;                      col = pv; }
            else if (j < 6)   { row = pv;                      col = topi_lds[k * KN + j - 1]; }
            else if (j < 11)  { row = topi_lds[k * KN + j - 6]; col = pv; }
            else { int q = j - 11; row = topi_lds[k * KN + q / KN]; col = topi_lds[k * KN + q % KN]; }
            unsigned a = (unsigned)(row * NN + col);
            modlist[i] = a;
            preval[i]  = W[a];
        }
    }
    if (tid < KS && sh_age[tid] < 5) s_lds[sh_pos[tid]] = 1.0f;   // same-value races benign
    __syncthreads();                      // P2 (drains gather loads + LDS)

    for (int k = 0; k < KS; ++k) {
        int prev = sh_pos[k];
        bool rowClean = (use_pre != 0) && (dirty[prev] == 0);   // block-uniform
        float r[4] = {0.f, 0.f, 0.f, 0.f};
        bool haveRow = false;
        int nxt;

        if (!rowClean) {
            // ---- FALLBACK: full row load + exact CDF recompute
            float4 rv = *((const float4*)(W + (size_t)prev * NN) + tid);
            r[0] = rv.x; r[1] = rv.y; r[2] = rv.z; r[3] = rv.w;
            haveRow = true;
            if (tid == 0) sh_nxt = NN - 1;  // default when t >= total
            double incl[4], a, ascan;
            cdf_scan(r, tid, lane, wid, wave_incl, incl, a, ascan);
            double waveExcl = (wid == 0) ? 0.0 : wave_incl[wid - 1];
            double total    = wave_incl[15];
            double thrIncl  = waveExcl + ascan;
            double thrExcl  = thrIncl - a;
            double t = (double)sh_u[k] * total;
            if (thrIncl > t && thrExcl <= t) {      // exactly one thread fires
                int found = 3;
                #pragma unroll
                for (int m = 0; m < 4; ++m)
                    if (thrExcl + incl[m] > t) { found = m; break; }
                sh_nxt = tid * 4 + found;
            }
            __syncthreads();                        // B3
            nxt = sh_nxt;
        } else {
            // ---- FAST PATH: draw fully precomputed on the pristine row
            nxt = prenxt_lds[k];
        }

        // need the full row for top-5 when dirty OR when the edge update hits
        // this very row (nxt == prev); load it BEFORE the edge write
        bool fullTop = !rowClean || (nxt == prev);   // block-uniform
        if (fullTop && !haveRow) {
            float4 rv = *((const float4*)(W + (size_t)prev * NN) + tid);
            r[0] = rv.x; r[1] = rv.y; r[2] = rv.z; r[3] = rv.w;
            haveRow = true;
            __syncthreads();   // loads complete before tid0's edge write below
        }

        // PREVAL eligibility: all 7 touched rows clean (no prior store can
        // have hit any of the 36 cells) and no intra-iteration cell overlap
        // (alias/edgeAlias), so each cell's new value = f(pristine value).
        int t0 = 0, t1 = 0, t2 = 0, t3 = 0, t4 = 0;
        bool usePreval = false, edgeAlias = false;
        if (!fullTop) {
            t0 = topi_lds[k * KN + 0]; t1 = topi_lds[k * KN + 1];
            t2 = topi_lds[k * KN + 2]; t3 = topi_lds[k * KN + 3];
            t4 = topi_lds[k * KN + 4];
            edgeAlias = (nxt == t0) || (nxt == t1) || (nxt == t2) ||
                        (nxt == t3) || (nxt == t4);
            bool aliasP = (prev == t0) || (prev == t1) || (prev == t2) ||
                          (prev == t3) || (prev == t4);
            bool dn = (dirty[nxt] | dirty[t0] | dirty[t1] |
                       dirty[t2]  | dirty[t3] | dirty[t4]) != 0;
            usePreval = !dn && !edgeAlias && !aliasP;
        }

        float sprev = s_lds[prev];
        if (usePreval) {
            // ---- zero-load path: 36 distinct cells, values from LDS
            if (tid < 36) {
                unsigned a = modlist[k * 36 + tid];
                float v = preval[k * 36 + tid];
                float nv = (tid == 0) ? (v * 0.95f + sprev * 0.05f)
                         : (tid < 6)  ? (v + 0.01f)
                         : (tid < 11) ? (v + 0.005f)
                                      : (v + 0.003f);
                W[a] = nv;
            }
            // modlist already correct from prologue prefill
        } else {
            // ---- live-RMW path (round-3 code, proven)
            if (tid == 0) {
                size_t o = (size_t)nxt * NN + prev;
                W[o] = W[o] * 0.95f + sprev * 0.05f;
            }
            if (fullTop) {
                if (nxt == prev && tid == (prev >> 2)) {   // register fix-up
                    int m = prev & 3;
                    r[m] = r[m] * 0.95f + sprev * 0.05f;
                }
                block_top5(r, tid, lane, wid, topv, topi, sh_top);  // B4+B5
                t0 = sh_top[0]; t1 = sh_top[1]; t2 = sh_top[2];
                t3 = sh_top[3]; t4 = sh_top[4];
            } else {
                // edge write ordered before ripple RMWs iff they can alias
                if (edgeAlias) __syncthreads();     // uniform condition
            }
            #define TOPQ(q) (fullTop ? sh_top[q] : topi_lds[k * KN + (q)])
            bool alias = (prev == t0) || (prev == t1) || (prev == t2) ||
                         (prev == t3) || (prev == t4);

            // ripples (plain stores; write-through L1 keeps them block-coherent)
            if (alias) {
                if (tid < KN) W[(size_t)prev * NN + TOPQ(tid)] += 0.01f;
                __syncthreads();
                if (tid < KN) W[(size_t)TOPQ(tid) * NN + prev] += 0.005f;
                __syncthreads();
                if (tid < KN * KN) W[(size_t)TOPQ(tid / KN) * NN + TOPQ(tid % KN)] += 0.003f;
            } else {
                if (tid < KN) {
                    W[(size_t)prev * NN + TOPQ(tid)] += 0.01f;
                    W[(size_t)TOPQ(tid) * NN + prev] += 0.005f;
                }
                if (tid >= 64 && tid < 64 + KN * KN) {
                    int q = tid - 64;
                    W[(size_t)TOPQ(q / KN) * NN + TOPQ(q % KN)] += 0.003f;
                }
            }

            // record modified W indices (overwrites clean-assumption prefill)
            if (tid < 36) {
                int row, col;
                if (tid == 0)       { row = nxt;             col = prev; }
                else if (tid < 6)   { row = prev;            col = TOPQ(tid - 1); }
                else if (tid < 11)  { row = TOPQ(tid - 6);   col = prev; }
                else { int q = tid - 11; row = TOPQ(q / KN); col = TOPQ(q % KN); }
                modlist[k * 36 + tid] = (unsigned)(row * NN + col);
            }
            #undef TOPQ
        }

        // ---- mark rows written this iteration (invalidates preval for them)
        if (tid == 0) { dirty[nxt] = 1; dirty[prev] = 1; }
        if (tid >= 128 && tid < 128 + KN) {
            int q = tid - 128;
            int tr = fullTop ? sh_top[q] : topi_lds[k * KN + q];
            dirty[tr] = 1;
        }

        // ---- energy decay, s deposit (pre-respawn), respawn bookkeeping
        if (tid == 0) {
            float en = sh_en[k] * 0.98f;
            s_lds[nxt] = en;
            int age = sh_age[k] + 1;
            int posn = nxt;
            if (en < 0.05f) { posn = k % NN; en = 1.0f; age = 0; }
            res_pos[k] = (float)posn;
            res_en[k]  = en;
            res_age[k] = (float)age;
        }
        __syncthreads();                        // B6: full drain (proven ordering)
    }

    // outputs: s, tail (pos/energy/age)
    ((float4*)out)[tid] = ((float4*)s_lds)[tid];
    if (tid < KS) {
        float* tail = out + NN + (size_t)NN * NN;
        tail[tid]          = res_pos[tid];
        tail[KS + tid]     = res_en[tid];
        tail[2 * KS + tid] = res_age[tid];
    }
    if (gridDim.x == 1) {
        // serial-fallback mode: decay already ran; fix up touched cells here
        float* outW = out + NN;
        for (int i = tid; i < KS * 36; i += 1024) {
            unsigned idx = modlist[i];
            float v = W[idx] * 0.999f;
            v = fminf(fmaxf(v, -2.f), 2.f);
            outW[idx] = v;   // duplicate indices write identical values: benign
        }
    } else {
        // combo mode: dump modlist; k_fix re-derives outW after the boundary
        for (int i = tid; i < KS * 36; i += 1024)
            ((unsigned*)(wsb + WS_MOD))[i] = modlist[i];
    }
}

// ---------------------------------------------------------------------------
// k_fix: after k_combo (kernel boundary = full coherence), re-derive the
// decayed output for every scan-modified W cell.
// ---------------------------------------------------------------------------
__global__ __launch_bounds__(576) void k_fix(const float* __restrict__ W,
                                             const char* __restrict__ wsb,
                                             float* __restrict__ out) {
    int i = blockIdx.x * 576 + threadIdx.x;     // 2 blocks x 576 = 1152
    unsigned idx = ((const unsigned*)(wsb + WS_MOD))[i];
    float v = W[idx] * 0.999f;
    v = fminf(fmaxf(v, -2.f), 2.f);
    (out + NN)[idx] = v;
}

extern "C" void kernel_launch(void* const* d_in, const int* in_sizes, int n_in,
                              void* d_out, int out_size, void* d_ws, size_t ws_size,
                              hipStream_t stream) {
    float*       W      = (float*)d_in[0];        // modified in place; harness restores
    const float* s      = (const float*)d_in[1];
    const float* noise  = (const float*)d_in[2];
    const float* energy = (const float*)d_in[3];
    const float* u      = (const float*)d_in[4];
    const int*   pos    = (const int*)d_in[5];
    const int*   age    = (const int*)d_in[6];
    float*       out    = (float*)d_out;

    if (ws_size >= WS_NEED) {
        float* s_ws = (float*)d_ws;               // s_new at ws offset 0
        k_mvpre<<<256 + KS, 1024, 0, stream>>>(W, s, noise, s_ws, pos, u, (char*)d_ws);
        k_combo<<<NB_COMBO, 1024, 0, stream>>>(W, s_ws, energy, u, pos, age,
                                               out, (char*)d_ws, 1);
        k_fix<<<2, 576, 0, stream>>>(W, (const char*)d_ws, out);
    } else {
        // serial fallback (round-7 proven): s_new staged in out[0..NN)
        k_front<<<NB_DEC, 1024, 0, stream>>>(W, s, noise, out, out + NN);
        k_combo<<<1, 1024, 0, stream>>>(W, out, energy, u, pos, age,
                                        out, (char*)d_ws, 0);
    }
}